// Round 6
// baseline (476.199 us; speedup 1.0000x reference)
//
#include <hip/hip_runtime.h>
#include <hip/hip_fp16.h>
#include <math.h>

// Problem constants (from reference)
#define B_TRAJ 16384
#define T_STEPS 60
#define D_IN 36
#define L_DIM 10
#define C_NUM 20
#define S_STAT 9
#define OUT_DIM 8

typedef __attribute__((ext_vector_type(2))) _Float16 h2;

__device__ __forceinline__ float rcp_fast(float x) { return __builtin_amdgcn_rcpf(x); }
__device__ __forceinline__ float sigm_fast(float x) { return rcp_fast(1.0f + __expf(-x)); }
__device__ __forceinline__ float tanh_fast(float x) {
    x = fminf(fmaxf(x, -10.0f), 10.0f);
    float e = __expf(2.0f * x);
    return (e - 1.0f) * rcp_fast(e + 1.0f);
}
__device__ __forceinline__ h2 f_as_h2(float f) { union { float f; h2 h; } u; u.f = f; return u.h; }
__device__ __forceinline__ float dot2(h2 a, h2 b, float c) {
#if __has_builtin(__builtin_amdgcn_fdot2)
    return __builtin_amdgcn_fdot2(a, b, c, false);
#else
    return c + (float)a.x * (float)b.x + (float)a.y * (float)b.y;
#endif
}
#define WFENCE() __builtin_amdgcn_wave_barrier()

// Phase 1: xproj[t][c] = x_t . Wx[:,c] computed from broadcast global float4
//          loads (no LDS staging), stored f16 in xprojH.
// Phase 2: sequential scan, 4 LDS round-trips/step; z carried UNNORMALIZED in
//          f16 (fdot2 consumes it); ODE y-dot fused with emitter y-dot.
// Phase 3: deferred MLP head from f16 y-history stashed into xprojH.
// Lane roles (s = lane & 31): s<10 u-col (+ODE col), 10..19 r-col (+emit col),
// 20..29 n-col (+emit col), 30/31 inert. All phase-2/3 sync intra-wave.
__global__ __launch_bounds__(256) __attribute__((amdgpu_waves_per_eu(5, 8)))
void dgm2_v6(
    const float* __restrict__ data,        // [B, T, D]
    const float* __restrict__ time_steps,  // [T]
    const float* __restrict__ static_data, // [B, S]
    const float* __restrict__ W_update,    // [46, 10]
    const float* __restrict__ b_update,
    const float* __restrict__ W_reset,     // [46, 10]
    const float* __restrict__ b_reset,
    const float* __restrict__ W_new,       // [46, 10]
    const float* __restrict__ b_new,
    const float* __restrict__ W_emit,      // [30, 20]
    const float* __restrict__ b_emit,
    const float* __restrict__ W_ode,       // [10, 10]
    const float* __restrict__ b_ode,
    const float* __restrict__ W_mlp,       // [609, 8]
    const float* __restrict__ b_mlp,
    float* __restrict__ out)               // [B, 8]
{
    __shared__ __align__(16) __half xprojH[8][61][30];   // 29280 B
    __shared__ __align__(16) float wbuf[4][2][64];       // 2048 B: per (wave,half):
                                                          //  [0..11] yi  [12..23] r  [24..35] n
                                                          //  [36..47] y  [48..57] z (20 halves)
    __shared__ float dts[64];

    const int tid  = threadIdx.x;
    const int w    = tid >> 6;
    const int lane = tid & 63;
    const int half = lane >> 5;
    const int s    = lane & 31;
    const int ltraj = w * 2 + half;
    const int traj  = blockIdx.x * 8 + ltraj;

    if (tid < T_STEPS) dts[tid] = (tid == 0) ? 0.01f : time_steps[tid] - time_steps[tid - 1];
    __syncthreads();    // dts produced by wave 0, consumed by all

    // ================= Phase 1: xproj via broadcast global loads =================
    {
        const float* Wsrc = (s < 10) ? W_update : ((s < 20) ? W_reset : W_new);
        const int cc = (s < 30) ? (s % 10) : 0;
        float wxp[D_IN];
#pragma unroll
        for (int k = 0; k < D_IN; ++k) wxp[k] = Wsrc[(L_DIM + k) * L_DIM + cc];

        const float* xb = data + (size_t)traj * (T_STEPS * D_IN);
        for (int t = 0; t < T_STEPS; ++t) {
            const float* xt = xb + t * D_IN;
            float acc = 0.0f;
#pragma unroll
            for (int g3 = 0; g3 < 3; ++g3) {
                const float4 a = *reinterpret_cast<const float4*>(xt + g3 * 12);
                const float4 b = *reinterpret_cast<const float4*>(xt + g3 * 12 + 4);
                const float4 c = *reinterpret_cast<const float4*>(xt + g3 * 12 + 8);
                const int k0 = g3 * 12;
                acc += a.x * wxp[k0 + 0] + a.y * wxp[k0 + 1] + a.z * wxp[k0 + 2] + a.w * wxp[k0 + 3]
                     + b.x * wxp[k0 + 4] + b.y * wxp[k0 + 5] + b.z * wxp[k0 + 6] + b.w * wxp[k0 + 7]
                     + c.x * wxp[k0 + 8] + c.y * wxp[k0 + 9] + c.z * wxp[k0 +10] + c.w * wxp[k0 +11];
            }
            if (s < 30) xprojH[ltraj][t][s] = __float2half(acc);
        }
    }
    WFENCE();   // xprojH is wave-local (own ltraj rows only)

    // ================= Phase 2: sequential scan =================
    const bool uo = (s < 10);
    const bool ro = (s >= 10 && s < 20);
    const bool no = (s >= 20 && s < 30);
    const bool eo = (s >= 10 && s < 30);
    const int  gcol = uo ? s : (ro ? (s - 10) : (no ? (s - 20) : 0));
    const int  ecol = s - 10;   // valid on eo lanes

    const float* Wg = uo ? W_update : (ro ? W_reset : W_new);
    float wgy[L_DIM];
#pragma unroll
    for (int k = 0; k < L_DIM; ++k) wgy[k] = (s < 30) ? Wg[k * L_DIM + gcol] : 0.0f;

    // wA: uo -> W_ode col s ; eo -> W_emit y-part col (rows 20..29). Used by the
    // fused dotA (end-of-step y dot == next step's ODE pre-activation).
    float wA[L_DIM];
#pragma unroll
    for (int k = 0; k < L_DIM; ++k) {
        float v = 0.0f;
        if (uo) v = W_ode[k * L_DIM + s];
        else if (eo) v = W_emit[(C_NUM + k) * C_NUM + ecol];
        wA[k] = v;
    }
    h2 wB[10];  // eo: W_emit p-part col, packed pairs (rows 2q, 2q+1)
#pragma unroll
    for (int q = 0; q < 10; ++q) {
        h2 v; v.x = (_Float16)0.0f; v.y = (_Float16)0.0f;
        if (eo) {
            v.x = (_Float16)W_emit[(2 * q) * C_NUM + ecol];
            v.y = (_Float16)W_emit[(2 * q + 1) * C_NUM + ecol];
        }
        wB[q] = v;
    }
    const float bg    = uo ? b_update[s] : (ro ? b_reset[gcol] : (no ? b_new[gcol] : 0.0f));
    const float bode  = uo ? b_ode[s] : 0.0f;
    const float bemit = eo ? b_emit[ecol] : 0.0f;

    float*  bcYI = &wbuf[w][half][0];
    float*  bcR  = &wbuf[w][half][12];
    float*  bcN  = &wbuf[w][half][24];
    float*  bcY  = &wbuf[w][half][36];
    __half* bcPH = reinterpret_cast<__half*>(&wbuf[w][half][48]);

    float y[L_DIM];
#pragma unroll
    for (int k = 0; k < L_DIM; ++k) y[k] = 0.0f;
    float yown = 0.0f;
    float dotA = 0.0f;              // y . wA carried across the step boundary
    if (eo) bcPH[ecol] = __float2half(0.0f);
    WFENCE();

    for (int t = 0; t < T_STEPS; ++t) {
        const float dt = dts[t];

        // ---- ODE (uo): yi_s = y_s + tanh(bode + dotA)*dt  (dotA = y.Wode_col) ----
        const float yis = fmaf(tanh_fast(bode + dotA), dt, yown);
        if (uo) bcYI[s] = yis;
        WFENCE();
        {
            const float4 a = *reinterpret_cast<const float4*>(bcYI);
            const float4 b = *reinterpret_cast<const float4*>(bcYI + 4);
            const float2 c = *reinterpret_cast<const float2*>(bcYI + 8);
            y[0] = a.x; y[1] = a.y; y[2] = a.z; y[3] = a.w;
            y[4] = b.x; y[5] = b.y; y[6] = b.z; y[7] = b.w;
            y[8] = c.x; y[9] = c.y;
        }

        // ---- gates: pre-act = bg + xproj(f16) + yi-part ----
        const float xa = (s < 30) ? __half2float(xprojH[ltraj][t][s]) : 0.0f;
        const float accB = bg + xa;
        float accY = 0.0f;
#pragma unroll
        for (int k = 0; k < L_DIM; ++k) accY += y[k] * wgy[k];
        const float uval = sigm_fast(accB + accY);   // u on uo, r on ro
        if (ro) bcR[s - 10] = uval;
        WFENCE();

        // ---- candidate (n lanes only — masked LDS reads) ----
        if (no) {
            const float4 a = *reinterpret_cast<const float4*>(bcR);
            const float4 b = *reinterpret_cast<const float4*>(bcR + 4);
            const float2 c = *reinterpret_cast<const float2*>(bcR + 8);
            const float rv[L_DIM] = {a.x, a.y, a.z, a.w, b.x, b.y, b.z, b.w, c.x, c.y};
            float accN = accB;
#pragma unroll
            for (int k = 0; k < L_DIM; ++k) accN += (y[k] * rv[k]) * wgy[k];
            bcN[s - 20] = accN;
        }
        WFENCE();

        // ---- blend (u lanes): yn = n + u*(yi-n); stash y_t f16 for phase 3 ----
        if (uo) {
            const float nv = bcN[s];
            const float yn = fmaf(uval, yis - nv, nv);
            yown = yn;
            bcY[s] = yn;
            xprojH[ltraj][t][s] = __float2half(yn);   // xproj[t] fully consumed
        }
        WFENCE();
        {
            const float4 a = *reinterpret_cast<const float4*>(bcY);
            const float4 b = *reinterpret_cast<const float4*>(bcY + 4);
            const float2 c = *reinterpret_cast<const float2*>(bcY + 8);
            y[0] = a.x; y[1] = a.y; y[2] = a.z; y[3] = a.w;
            y[4] = b.x; y[5] = b.y; y[6] = b.z; y[7] = b.w;
            y[8] = c.x; y[9] = c.y;
        }

        // ---- fused dotA = y_new . wA  (emitter y-part now; ODE pre-act next t) ----
        float dA = 0.0f;
#pragma unroll
        for (int k = 0; k < L_DIM; ++k) dA += y[k] * wA[k];
        dotA = dA;

        // ---- emitter: logit = bemit + (z.We_p)/sum(z) + dA ; z carried f16 ----
        const float4 za = *reinterpret_cast<const float4*>(bcPH);       // halves 0..7
        const float4 zb = *reinterpret_cast<const float4*>(bcPH + 8);   // 8..15
        const float2 zc = *reinterpret_cast<const float2*>(bcPH + 16);  // 16..19
        h2 zp[10];
        zp[0] = f_as_h2(za.x); zp[1] = f_as_h2(za.y); zp[2] = f_as_h2(za.z); zp[3] = f_as_h2(za.w);
        zp[4] = f_as_h2(zb.x); zp[5] = f_as_h2(zb.y); zp[6] = f_as_h2(zb.z); zp[7] = f_as_h2(zb.w);
        zp[8] = f_as_h2(zc.x); zp[9] = f_as_h2(zc.y);
        h2 one2; one2.x = (_Float16)1.0f; one2.y = (_Float16)1.0f;
        float zdot = 0.0f, zsum = 0.0f;
#pragma unroll
        for (int q = 0; q < 10; ++q) {
            zdot = dot2(zp[q], wB[q], zdot);
            zsum = dot2(zp[q], one2, zsum);
        }
        const float pinv = (t == 0) ? 0.0f : rcp_fast(zsum);
        const float ev = fmaf(zdot, pinv, bemit) + dA;
        const float zv = __expf(fminf(ev, 11.0f));    // e^11 < f16 max
        if (eo) bcPH[ecol] = __float2half(zv);
        WFENCE();
    }

    // ================= Phase 3: deferred MLP head =================
    {
        const int g = s >> 3, col = s & 7;
        float o8 = 0.0f;
        for (int tb = 0; tb < 15; ++tb) {
            const int t = g + tb * 4;
            const __half2* yh = reinterpret_cast<const __half2*>(&xprojH[ltraj][t][0]);
            const float* wrow = W_mlp + (size_t)t * L_DIM * OUT_DIM + col;
#pragma unroll
            for (int q = 0; q < 5; ++q) {
                const float2 yv = __half22float2(yh[q]);
                o8 += yv.x * wrow[(2 * q) * OUT_DIM] + yv.y * wrow[(2 * q + 1) * OUT_DIM];
            }
        }
        o8 += __shfl_xor(o8, 8, 32);
        o8 += __shfl_xor(o8, 16, 32);
        if (s < OUT_DIM) {
            const float* stp = static_data + (size_t)traj * S_STAT;
            const float* wms = W_mlp + (size_t)(T_STEPS * L_DIM) * OUT_DIM;
#pragma unroll
            for (int i = 0; i < S_STAT; ++i) o8 += stp[i] * wms[i * OUT_DIM + s];
            out[(size_t)traj * OUT_DIM + s] = o8 + b_mlp[s];
        }
    }
}

extern "C" void kernel_launch(void* const* d_in, const int* in_sizes, int n_in,
                              void* d_out, int out_size, void* d_ws, size_t ws_size,
                              hipStream_t stream) {
    const float* data        = (const float*)d_in[0];
    const float* time_steps  = (const float*)d_in[1];
    const float* static_data = (const float*)d_in[2];
    const float* W_update    = (const float*)d_in[3];
    const float* b_update    = (const float*)d_in[4];
    const float* W_reset     = (const float*)d_in[5];
    const float* b_reset     = (const float*)d_in[6];
    const float* W_new       = (const float*)d_in[7];
    const float* b_new       = (const float*)d_in[8];
    const float* W_emit      = (const float*)d_in[9];
    const float* b_emit      = (const float*)d_in[10];
    const float* W_ode       = (const float*)d_in[11];
    const float* b_ode       = (const float*)d_in[12];
    const float* W_mlp       = (const float*)d_in[13];
    const float* b_mlp       = (const float*)d_in[14];
    float* out = (float*)d_out;

    // 8 trajectories per 256-thread block -> 2048 blocks, 8192 waves
    dim3 grid(B_TRAJ / 8), block(256);
    hipLaunchKernelGGL(dgm2_v6, grid, block, 0, stream,
                       data, time_steps, static_data,
                       W_update, b_update, W_reset, b_reset, W_new, b_new,
                       W_emit, b_emit, W_ode, b_ode, W_mlp, b_mlp, out);
}

// Round 7
// 344.096 us; speedup vs baseline: 1.3839x; 1.3839x over previous
//
#include <hip/hip_runtime.h>
#include <hip/hip_fp16.h>
#include <math.h>

// Problem constants (from reference)
#define B_TRAJ 16384
#define T_STEPS 60
#define D_IN 36
#define L_DIM 10
#define C_NUM 20
#define S_STAT 9
#define OUT_DIM 8
#define TT 2
#define NTILE (T_STEPS / TT)   // 30

typedef __attribute__((ext_vector_type(2))) _Float16 h2;

__device__ __forceinline__ float rcp_fast(float x) { return __builtin_amdgcn_rcpf(x); }
__device__ __forceinline__ float sigm_fast(float x) { return rcp_fast(1.0f + __expf(-x)); }
__device__ __forceinline__ float tanh_fast(float x) {
    x = fminf(fmaxf(x, -10.0f), 10.0f);
    float e = __expf(2.0f * x);
    return (e - 1.0f) * rcp_fast(e + 1.0f);
}
__device__ __forceinline__ h2 f_as_h2(float f) { union { float f; h2 h; } u; u.f = f; return u.h; }
__device__ __forceinline__ float dot2(h2 a, h2 b, float c) {
#if __has_builtin(__builtin_amdgcn_fdot2)
    return __builtin_amdgcn_fdot2(a, b, c, false);
#else
    return c + (float)a.x * (float)b.x + (float)a.y * (float)b.y;
#endif
}
#define WFENCE() __builtin_amdgcn_wave_barrier()

// v7 = v5 phase 1 (LDS-staged x + WGX weight tile; spill-safe) +
//      v6 phase 2 (fused dotA, f16 unnormalized z via fdot2, masked candidate) +
//      waves_per_eu(4,4) (explicit 128-VGPR budget) + 38.8 KB LDS (4 blocks/CU).
// Lane roles (s = lane & 31): s<10 u-col (+ODE col), 10..19 r-col (+emit col),
// 20..29 n-col (+emit col), 30/31 inert. All phase-2/3 sync intra-wave.
__global__ __launch_bounds__(256) __attribute__((amdgpu_waves_per_eu(4, 4)))
void dgm2_v7(
    const float* __restrict__ data,        // [B, T, D]
    const float* __restrict__ time_steps,  // [T]
    const float* __restrict__ static_data, // [B, S]
    const float* __restrict__ W_update,    // [46, 10]
    const float* __restrict__ b_update,
    const float* __restrict__ W_reset,     // [46, 10]
    const float* __restrict__ b_reset,
    const float* __restrict__ W_new,       // [46, 10]
    const float* __restrict__ b_new,
    const float* __restrict__ W_emit,      // [30, 20]
    const float* __restrict__ b_emit,
    const float* __restrict__ W_ode,       // [10, 10]
    const float* __restrict__ b_ode,
    const float* __restrict__ W_mlp,       // [609, 8]
    const float* __restrict__ b_mlp,
    float* __restrict__ out)               // [B, 8]
{
    __shared__ __align__(16) __half xprojH[8][61][30];   // 29280 B
    __shared__ __align__(16) float WGX[D_IN][32];        // 4608 B (phase-1 x-weights)
    __shared__ __align__(16) float wbuf[4][292];         // 4672 B per-wave scratch:
                                                          //  phase1: xstage [buf][half][tt][36] (288 f)
                                                          //  phase2: yi@0 r@24 n@48 y@72 (+half*12), z(f16)@96 (+half*20h)
    __shared__ float dts[64];

    const int tid  = threadIdx.x;
    const int w    = tid >> 6;
    const int lane = tid & 63;
    const int half = lane >> 5;
    const int s    = lane & 31;
    const int ltraj = w * 2 + half;
    const int traj  = blockIdx.x * 8 + ltraj;

    // ---- block-wide one-time: WGX + dts ----
    for (int i = tid; i < D_IN * 30; i += 256) {
        const int k = i / 30, c = i % 30;
        float v;
        if (c < 10)      v = W_update[(L_DIM + k) * L_DIM + c];
        else if (c < 20) v = W_reset [(L_DIM + k) * L_DIM + (c - 10)];
        else             v = W_new   [(L_DIM + k) * L_DIM + (c - 20)];
        WGX[k][c] = v;
    }
    for (int i = tid; i < D_IN * 2; i += 256) WGX[i >> 1][30 + (i & 1)] = 0.0f;
    if (tid < T_STEPS) dts[tid] = (tid == 0) ? 0.01f : time_steps[tid] - time_steps[tid - 1];
    __syncthreads();

    // ================= Phase 1: xproj precompute (wave-local, LDS-staged) =================
    {
        float wxp[D_IN];
#pragma unroll
        for (int k = 0; k < D_IN; ++k) wxp[k] = WGX[k][s];

        float* xst = &wbuf[w][0];   // [buf][half][tt][36]
        const float* tbase = data + (size_t)(blockIdx.x * 8 + w * 2) * (T_STEPS * D_IN);
        const int sh  = lane / 18;      // staging half
        const int sr  = lane % 18;
        const int stt = sr / 9;         // timestep within tile
        const int sc  = sr % 9;         // float4 chunk
        const bool stg = (lane < 36);

        if (stg) {
            const float4 v = *reinterpret_cast<const float4*>(
                tbase + (size_t)sh * (T_STEPS * D_IN) + stt * D_IN + sc * 4);
            *reinterpret_cast<float4*>(xst + ((0 * 2 + sh) * TT + stt) * 36 + sc * 4) = v;
        }
        WFENCE();

        for (int tile = 0; tile < NTILE; ++tile) {
            const int cb = tile & 1, nb = cb ^ 1;
            float4 pf = make_float4(0.f, 0.f, 0.f, 0.f);
            if (stg && (tile + 1 < NTILE)) {
                pf = *reinterpret_cast<const float4*>(
                    tbase + (size_t)sh * (T_STEPS * D_IN) + ((tile + 1) * TT + stt) * D_IN + sc * 4);
            }
#pragma unroll
            for (int tt = 0; tt < TT; ++tt) {
                const float* xrow = xst + ((cb * 2 + half) * TT + tt) * 36;
                float acc = 0.0f;
#pragma unroll
                for (int c = 0; c < 9; ++c) {
                    const float4 x4 = *reinterpret_cast<const float4*>(xrow + c * 4);
                    acc += x4.x * wxp[c * 4]     + x4.y * wxp[c * 4 + 1]
                         + x4.z * wxp[c * 4 + 2] + x4.w * wxp[c * 4 + 3];
                }
                if (s < 30) xprojH[ltraj][tile * TT + tt][s] = __float2half(acc);
            }
            if (stg && (tile + 1 < NTILE)) {
                *reinterpret_cast<float4*>(xst + ((nb * 2 + sh) * TT + stt) * 36 + sc * 4) = pf;
            }
            WFENCE();
        }
    }

    // ================= Phase 2: sequential scan =================
    const bool uo = (s < 10);
    const bool ro = (s >= 10 && s < 20);
    const bool no = (s >= 20 && s < 30);
    const bool eo = (s >= 10 && s < 30);
    const int  gcol = uo ? s : (ro ? (s - 10) : (no ? (s - 20) : 0));
    const int  ecol = s - 10;   // valid on eo lanes

    const float* Wg = uo ? W_update : (ro ? W_reset : W_new);
    float wgy[L_DIM];
#pragma unroll
    for (int k = 0; k < L_DIM; ++k) wgy[k] = (s < 30) ? Wg[k * L_DIM + gcol] : 0.0f;

    // wA: uo -> W_ode col s ; eo -> W_emit y-part col. Fused dotA = y_new . wA
    // doubles as next step's ODE pre-activation (uo) and emitter y-part (eo).
    float wA[L_DIM];
#pragma unroll
    for (int k = 0; k < L_DIM; ++k) {
        float v = 0.0f;
        if (uo) v = W_ode[k * L_DIM + s];
        else if (eo) v = W_emit[(C_NUM + k) * C_NUM + ecol];
        wA[k] = v;
    }
    h2 wB[10];  // eo: W_emit p-part col, packed pairs (rows 2q, 2q+1)
#pragma unroll
    for (int q = 0; q < 10; ++q) {
        h2 v; v.x = (_Float16)0.0f; v.y = (_Float16)0.0f;
        if (eo) {
            v.x = (_Float16)W_emit[(2 * q) * C_NUM + ecol];
            v.y = (_Float16)W_emit[(2 * q + 1) * C_NUM + ecol];
        }
        wB[q] = v;
    }
    const float bg    = uo ? b_update[s] : (ro ? b_reset[gcol] : (no ? b_new[gcol] : 0.0f));
    const float bode  = uo ? b_ode[s] : 0.0f;
    const float bemit = eo ? b_emit[ecol] : 0.0f;

    float*  bcYI = &wbuf[w][0]  + half * 12;
    float*  bcR  = &wbuf[w][24] + half * 12;
    float*  bcN  = &wbuf[w][48] + half * 12;
    float*  bcY  = &wbuf[w][72] + half * 12;
    __half* bcPH = reinterpret_cast<__half*>(&wbuf[w][96]) + half * 20;

    float y[L_DIM];
#pragma unroll
    for (int k = 0; k < L_DIM; ++k) y[k] = 0.0f;
    float yown = 0.0f;
    float dotA = 0.0f;              // y . wA carried across the step boundary
    if (eo) bcPH[ecol] = __float2half(0.0f);
    WFENCE();

    for (int t = 0; t < T_STEPS; ++t) {
        const float dt = dts[t];

        // ---- ODE (uo): yi_s = y_s + tanh(bode + dotA)*dt ----
        const float yis = fmaf(tanh_fast(bode + dotA), dt, yown);
        if (uo) bcYI[s] = yis;
        WFENCE();
        {
            const float4 a = *reinterpret_cast<const float4*>(bcYI);
            const float4 b = *reinterpret_cast<const float4*>(bcYI + 4);
            const float2 c = *reinterpret_cast<const float2*>(bcYI + 8);
            y[0] = a.x; y[1] = a.y; y[2] = a.z; y[3] = a.w;
            y[4] = b.x; y[5] = b.y; y[6] = b.z; y[7] = b.w;
            y[8] = c.x; y[9] = c.y;
        }

        // ---- gates: pre-act = bg + xproj(f16) + yi-part ----
        const float xa = (s < 30) ? __half2float(xprojH[ltraj][t][s]) : 0.0f;
        const float accB = bg + xa;
        float accY = 0.0f;
#pragma unroll
        for (int k = 0; k < L_DIM; ++k) accY += y[k] * wgy[k];
        const float uval = sigm_fast(accB + accY);   // u on uo, r on ro
        if (ro) bcR[s - 10] = uval;
        WFENCE();

        // ---- candidate (n lanes only — masked LDS reads) ----
        if (no) {
            const float4 a = *reinterpret_cast<const float4*>(bcR);
            const float4 b = *reinterpret_cast<const float4*>(bcR + 4);
            const float2 c = *reinterpret_cast<const float2*>(bcR + 8);
            const float rv[L_DIM] = {a.x, a.y, a.z, a.w, b.x, b.y, b.z, b.w, c.x, c.y};
            float accN = accB;
#pragma unroll
            for (int k = 0; k < L_DIM; ++k) accN += (y[k] * rv[k]) * wgy[k];
            bcN[s - 20] = accN;
        }
        WFENCE();

        // ---- blend (u lanes): yn = n + u*(yi-n); stash y_t f16 for phase 3 ----
        if (uo) {
            const float nv = bcN[s];
            const float yn = fmaf(uval, yis - nv, nv);
            yown = yn;
            bcY[s] = yn;
            xprojH[ltraj][t][s] = __float2half(yn);   // xproj[t] fully consumed
        }
        WFENCE();
        {
            const float4 a = *reinterpret_cast<const float4*>(bcY);
            const float4 b = *reinterpret_cast<const float4*>(bcY + 4);
            const float2 c = *reinterpret_cast<const float2*>(bcY + 8);
            y[0] = a.x; y[1] = a.y; y[2] = a.z; y[3] = a.w;
            y[4] = b.x; y[5] = b.y; y[6] = b.z; y[7] = b.w;
            y[8] = c.x; y[9] = c.y;
        }

        // ---- fused dotA = y_new . wA (emitter y-part now; ODE pre-act next t) ----
        float dA = 0.0f;
#pragma unroll
        for (int k = 0; k < L_DIM; ++k) dA += y[k] * wA[k];
        dotA = dA;

        // ---- emitter: logit = bemit + (z.We_p)/sum(z) + dA ; z carried f16 ----
        const float4 za = *reinterpret_cast<const float4*>(bcPH);       // halves 0..7
        const float4 zb = *reinterpret_cast<const float4*>(bcPH + 8);   // 8..15
        const float2 zc = *reinterpret_cast<const float2*>(bcPH + 16);  // 16..19
        h2 zp[10];
        zp[0] = f_as_h2(za.x); zp[1] = f_as_h2(za.y); zp[2] = f_as_h2(za.z); zp[3] = f_as_h2(za.w);
        zp[4] = f_as_h2(zb.x); zp[5] = f_as_h2(zb.y); zp[6] = f_as_h2(zb.z); zp[7] = f_as_h2(zb.w);
        zp[8] = f_as_h2(zc.x); zp[9] = f_as_h2(zc.y);
        h2 one2; one2.x = (_Float16)1.0f; one2.y = (_Float16)1.0f;
        float zdot = 0.0f, zsum = 0.0f;
#pragma unroll
        for (int q = 0; q < 10; ++q) {
            zdot = dot2(zp[q], wB[q], zdot);
            zsum = dot2(zp[q], one2, zsum);
        }
        const float pinv = (t == 0) ? 0.0f : rcp_fast(zsum);
        const float ev = fmaf(zdot, pinv, bemit) + dA;
        const float zv = __expf(fminf(ev, 11.0f));    // e^11 < f16 max
        if (eo) bcPH[ecol] = __float2half(zv);
        WFENCE();
    }

    // ================= Phase 3: deferred MLP head =================
    {
        const int g = s >> 3, col = s & 7;
        float o8 = 0.0f;
        for (int tb = 0; tb < 15; ++tb) {
            const int t = g + tb * 4;
            const __half2* yh = reinterpret_cast<const __half2*>(&xprojH[ltraj][t][0]);
            const float* wrow = W_mlp + (size_t)t * L_DIM * OUT_DIM + col;
#pragma unroll
            for (int q = 0; q < 5; ++q) {
                const float2 yv = __half22float2(yh[q]);
                o8 += yv.x * wrow[(2 * q) * OUT_DIM] + yv.y * wrow[(2 * q + 1) * OUT_DIM];
            }
        }
        o8 += __shfl_xor(o8, 8, 32);
        o8 += __shfl_xor(o8, 16, 32);
        if (s < OUT_DIM) {
            const float* stp = static_data + (size_t)traj * S_STAT;
            const float* wms = W_mlp + (size_t)(T_STEPS * L_DIM) * OUT_DIM;
#pragma unroll
            for (int i = 0; i < S_STAT; ++i) o8 += stp[i] * wms[i * OUT_DIM + s];
            out[(size_t)traj * OUT_DIM + s] = o8 + b_mlp[s];
        }
    }
}

extern "C" void kernel_launch(void* const* d_in, const int* in_sizes, int n_in,
                              void* d_out, int out_size, void* d_ws, size_t ws_size,
                              hipStream_t stream) {
    const float* data        = (const float*)d_in[0];
    const float* time_steps  = (const float*)d_in[1];
    const float* static_data = (const float*)d_in[2];
    const float* W_update    = (const float*)d_in[3];
    const float* b_update    = (const float*)d_in[4];
    const float* W_reset     = (const float*)d_in[5];
    const float* b_reset     = (const float*)d_in[6];
    const float* W_new       = (const float*)d_in[7];
    const float* b_new       = (const float*)d_in[8];
    const float* W_emit      = (const float*)d_in[9];
    const float* b_emit      = (const float*)d_in[10];
    const float* W_ode       = (const float*)d_in[11];
    const float* b_ode       = (const float*)d_in[12];
    const float* W_mlp       = (const float*)d_in[13];
    const float* b_mlp       = (const float*)d_in[14];
    float* out = (float*)d_out;

    // 8 trajectories per 256-thread block -> 2048 blocks, 8192 waves
    dim3 grid(B_TRAJ / 8), block(256);
    hipLaunchKernelGGL(dgm2_v7, grid, block, 0, stream,
                       data, time_steps, static_data,
                       W_update, b_update, W_reset, b_reset, W_new, b_new,
                       W_emit, b_emit, W_ode, b_ode, W_mlp, b_mlp, out);
}